// Round 9
// baseline (41.967 us; speedup 1.0000x reference)
//
#include <hip/hip_runtime.h>
#include <math.h>

// Problem constants (from reference):
constexpr int Bn = 1024;
constexpr int S  = 512;
constexpr int H  = 768;
constexpr int D1 = 128;
constexpr int HV = H / 4;     // 192 float4 per feature row
constexpr int NPOOL = Bn * 2; // pool blocks in launch 1 (dispatched first)

// ws layout (floats):
//   gp [2][Bn][768]  — span-mean partials (even/odd rows), pre-scaled by 1/len
//   P  [2][Bn][D1]   — CLS-half partial h dots (chunks 0,1)

// Launch 1: fat kernel. Blocks [0, NPOOL) = R2-exact pool (HBM stream starts
// immediately); blocks [NPOOL, NPOOL+512) = CLS-half head (latency-bound
// backfill that hides under the pool's HBM stalls).
__global__ __launch_bounds__(256) void fused_pool_clshead(
    const float* __restrict__ feat, const int* __restrict__ start,
    const int* __restrict__ endp, float* __restrict__ gp,
    const float* __restrict__ W1, float* __restrict__ P) {
  __shared__ float g[4][384];        // 6 KB (head path only)
  __shared__ float part[2][4][D1];   // 4 KB

  const int t = threadIdx.x;

  if (blockIdx.x >= NPOOL) {
    // ---- CLS-half head: chunk c in {0,1}, 4 examples ----
    const int hb = blockIdx.x - NPOOL;
    const int c = hb & 1;
    const int e0 = (hb >> 1) * 4;
    const int dglob0 = c * 384;

    for (int i = t; i < 384; i += 256) {
      const int e = i / 96;          // 96 float4 per example-chunk
      const int j = i % 96;
      float4 v = *reinterpret_cast<const float4*>(
          feat + (size_t)(e0 + e) * S * H + dglob0 + j * 4);
      reinterpret_cast<float4*>(&g[e][0])[j] = v;
    }
    __syncthreads();

    const int k = t & (D1 - 1);
    const int sub = t >> 7;
    const int gofs = sub * 192;
    const float* Wc = W1 + (size_t)(dglob0 + gofs) * D1 + k;

    float a0 = 0.f, a1 = 0.f, a2 = 0.f, a3 = 0.f;
    #pragma unroll 4
    for (int d = 0; d < 192; d += 4) {
      float w0 = Wc[(size_t)(d + 0) * D1];
      float w1 = Wc[(size_t)(d + 1) * D1];
      float w2 = Wc[(size_t)(d + 2) * D1];
      float w3 = Wc[(size_t)(d + 3) * D1];
      float4 g0 = *reinterpret_cast<const float4*>(&g[0][gofs + d]);
      float4 g1 = *reinterpret_cast<const float4*>(&g[1][gofs + d]);
      float4 g2 = *reinterpret_cast<const float4*>(&g[2][gofs + d]);
      float4 g3 = *reinterpret_cast<const float4*>(&g[3][gofs + d]);
      a0 += g0.x * w0 + g0.y * w1 + g0.z * w2 + g0.w * w3;
      a1 += g1.x * w0 + g1.y * w1 + g1.z * w2 + g1.w * w3;
      a2 += g2.x * w0 + g2.y * w1 + g2.z * w2 + g2.w * w3;
      a3 += g3.x * w0 + g3.y * w1 + g3.z * w2 + g3.w * w3;
    }
    part[sub][0][k] = a0;
    part[sub][1][k] = a1;
    part[sub][2][k] = a2;
    part[sub][3][k] = a3;
    __syncthreads();

    if (t < D1) {
      #pragma unroll
      for (int e = 0; e < 4; ++e) {
        P[((size_t)c * Bn + (e0 + e)) * D1 + t] = part[0][e][t] + part[1][e][t];
      }
    }
    return;
  }

  // ---- pool: R2-exact span mean-pool ----
  if (t >= 192) return;              // wave 3 retires immediately
  const int bb = blockIdx.x;
  const int b = bb >> 1;
  const int p = bb & 1;
  const float4* base = reinterpret_cast<const float4*>(feat) + (size_t)b * (S * HV);

  const int s0 = start[b];
  const int s1 = endp[b];
  float4 a0{0,0,0,0}, a1{0,0,0,0}, a2{0,0,0,0}, a3{0,0,0,0};
  int s = s0 + p;
  for (; s + 6 < s1; s += 8) {
    float4 v0 = base[(size_t)(s    ) * HV + t];
    float4 v1 = base[(size_t)(s + 2) * HV + t];
    float4 v2 = base[(size_t)(s + 4) * HV + t];
    float4 v3 = base[(size_t)(s + 6) * HV + t];
    a0.x += v0.x; a0.y += v0.y; a0.z += v0.z; a0.w += v0.w;
    a1.x += v1.x; a1.y += v1.y; a1.z += v1.z; a1.w += v1.w;
    a2.x += v2.x; a2.y += v2.y; a2.z += v2.z; a2.w += v2.w;
    a3.x += v3.x; a3.y += v3.y; a3.z += v3.z; a3.w += v3.w;
  }
  for (; s < s1; s += 2) {
    float4 v = base[(size_t)s * HV + t];
    a0.x += v.x; a0.y += v.y; a0.z += v.z; a0.w += v.w;
  }
  const float inv = 1.0f / (float)(s1 - s0);
  float4 r;
  r.x = ((a0.x + a1.x) + (a2.x + a3.x)) * inv;
  r.y = ((a0.y + a1.y) + (a2.y + a3.y)) * inv;
  r.z = ((a0.z + a1.z) + (a2.z + a3.z)) * inv;
  r.w = ((a0.w + a1.w) + (a2.w + a3.w)) * inv;
  reinterpret_cast<float4*>(gp)[((size_t)p * Bn + b) * HV + t] = r;
}

// Launch 2: CRC head + finalize fused. Block = 2 whole examples (both CRC
// chunks), grid 512 x 256 thr. After the partial dots, reads the CLS-half
// partials P[0..1] (L2-hot) and produces the final sigmoid output directly.
__global__ __launch_bounds__(256) void crc_head_finalize(
    const float* __restrict__ gp, const float* __restrict__ W1,
    const float* __restrict__ P, const float* __restrict__ b1,
    const float* __restrict__ W2, const float* __restrict__ b2,
    float* __restrict__ out) {
  __shared__ float g[2][768];        // 6 KB: 2 examples' full CRC features
  __shared__ float part[2][2][D1];   // 2 KB: [sub][e][k]
  __shared__ float wsum[4];

  const int t = threadIdx.x;
  const int e0 = blockIdx.x * 2;

  // Stage g: crc = gp0 + gp1 for 2 examples (384 float4)
  for (int i = t; i < 384; i += 256) {
    const int e = i / 192;
    const int j = i % 192;
    const float* b0 = gp + (size_t)(e0 + e) * H;
    float4 u0 = reinterpret_cast<const float4*>(b0)[j];
    float4 u1 = reinterpret_cast<const float4*>(b0 + (size_t)Bn * H)[j];
    float4 v;
    v.x = u0.x + u1.x; v.y = u0.y + u1.y;
    v.z = u0.z + u1.z; v.w = u0.w + u1.w;
    reinterpret_cast<float4*>(&g[e][0])[j] = v;
  }
  __syncthreads();

  const int k = t & (D1 - 1);
  const int sub = t >> 7;            // which 384-d half of the CRC
  const int gofs = sub * 384;
  const float* Wc = W1 + (size_t)(H + gofs) * D1 + k;

  float a0 = 0.f, a1 = 0.f;
  #pragma unroll 4
  for (int d = 0; d < 384; d += 4) {
    float w0 = Wc[(size_t)(d + 0) * D1];
    float w1 = Wc[(size_t)(d + 1) * D1];
    float w2 = Wc[(size_t)(d + 2) * D1];
    float w3 = Wc[(size_t)(d + 3) * D1];
    float4 g0 = *reinterpret_cast<const float4*>(&g[0][gofs + d]);
    float4 g1 = *reinterpret_cast<const float4*>(&g[1][gofs + d]);
    a0 += g0.x * w0 + g0.y * w1 + g0.z * w2 + g0.w * w3;
    a1 += g1.x * w0 + g1.y * w1 + g1.z * w2 + g1.w * w3;
  }
  part[sub][0][k] = a0;
  part[sub][1][k] = a1;
  __syncthreads();

  // Finalize: thread = (e = t>>7, k = t&127); combine CLS partials (P) +
  // CRC partials, relu, W2 dot, reduce 128 k across 2 waves per example.
  {
    const int e = t >> 7;
    const int kk = t & (D1 - 1);
    float h = b1[kk] + part[0][e][kk] + part[1][e][kk]
            + P[((size_t)0 * Bn + (e0 + e)) * D1 + kk]
            + P[((size_t)1 * Bn + (e0 + e)) * D1 + kk];
    h = fmaxf(h, 0.f);
    float v = h * W2[kk];
    #pragma unroll
    for (int off = 32; off > 0; off >>= 1) v += __shfl_down(v, off);
    if ((t & 63) == 0) wsum[t >> 6] = v;
  }
  __syncthreads();

  if (t < 2) {
    float s = wsum[2 * t] + wsum[2 * t + 1] + b2[0];
    out[e0 + t] = 1.0f / (1.0f + expf(-s));
  }
}

extern "C" void kernel_launch(void* const* d_in, const int* in_sizes, int n_in,
                              void* d_out, int out_size, void* d_ws, size_t ws_size,
                              hipStream_t stream) {
  const float* feat = (const float*)d_in[0];   // [B,S,H] fp32
  const int* start  = (const int*)d_in[1];     // [B]
  const int* endp   = (const int*)d_in[2];     // [B]
  const float* W1   = (const float*)d_in[3];   // [2H,D1]
  const float* b1   = (const float*)d_in[4];   // [D1]
  const float* W2   = (const float*)d_in[5];   // [D1,1]
  const float* b2   = (const float*)d_in[6];   // [1]
  float* out = (float*)d_out;                  // [B]

  float* wsf = (float*)d_ws;
  float* gp  = wsf;                            // [2][Bn][768]
  float* P   = gp + (size_t)2 * Bn * H;        // [2][Bn][D1]

  hipLaunchKernelGGL(fused_pool_clshead, dim3(NPOOL + 512), dim3(256), 0,
                     stream, feat, start, endp, gp, W1, P);
  hipLaunchKernelGGL(crc_head_finalize, dim3(Bn / 2), dim3(256), 0, stream,
                     gp, W1, P, b1, W2, b2, out);
}

// Round 10
// 36.927 us; speedup vs baseline: 1.1365x; 1.1365x over previous
//
#include <hip/hip_runtime.h>
#include <math.h>

// Problem constants (from reference):
constexpr int Bn = 1024;
constexpr int S  = 512;
constexpr int H  = 768;
constexpr int D1 = 128;
constexpr int HV = H / 4;     // 192 float4 per feature row
constexpr int NH = 512;       // cls-head blocks fused into launch 1

// ws layout (floats):
//   gp [2][Bn][768]  — span-mean partials (even/odd rows), pre-scaled by 1/len
//   P  [2][Bn][D1]   — CLS-half partial h dots (chunks 0,1)

// Launch 1 (R8-exact): blocks [0,NH) = CLS-half head; [NH,NH+2048) = pool.
__global__ __launch_bounds__(256) void fused_pool_clshead(
    const float* __restrict__ feat, const int* __restrict__ start,
    const int* __restrict__ endp, float* __restrict__ gp,
    const float* __restrict__ W1, float* __restrict__ P) {
  __shared__ float g[4][384];        // 6 KB (head path only)
  __shared__ float part[2][4][D1];   // 4 KB

  const int t = threadIdx.x;

  if (blockIdx.x < NH) {
    // ---- CLS-half head: chunk c in {0,1}, 4 examples ----
    const int c = blockIdx.x & 1;
    const int e0 = (blockIdx.x >> 1) * 4;
    const int dglob0 = c * 384;

    for (int i = t; i < 384; i += 256) {
      const int e = i / 96;          // 96 float4 per example-chunk
      const int j = i % 96;
      float4 v = *reinterpret_cast<const float4*>(
          feat + (size_t)(e0 + e) * S * H + dglob0 + j * 4);
      reinterpret_cast<float4*>(&g[e][0])[j] = v;
    }
    __syncthreads();

    const int k = t & (D1 - 1);
    const int sub = t >> 7;
    const int gofs = sub * 192;
    const float* Wc = W1 + (size_t)(dglob0 + gofs) * D1 + k;

    float a0 = 0.f, a1 = 0.f, a2 = 0.f, a3 = 0.f;
    #pragma unroll 4
    for (int d = 0; d < 192; d += 4) {
      float w0 = Wc[(size_t)(d + 0) * D1];
      float w1 = Wc[(size_t)(d + 1) * D1];
      float w2 = Wc[(size_t)(d + 2) * D1];
      float w3 = Wc[(size_t)(d + 3) * D1];
      float4 g0 = *reinterpret_cast<const float4*>(&g[0][gofs + d]);
      float4 g1 = *reinterpret_cast<const float4*>(&g[1][gofs + d]);
      float4 g2 = *reinterpret_cast<const float4*>(&g[2][gofs + d]);
      float4 g3 = *reinterpret_cast<const float4*>(&g[3][gofs + d]);
      a0 += g0.x * w0 + g0.y * w1 + g0.z * w2 + g0.w * w3;
      a1 += g1.x * w0 + g1.y * w1 + g1.z * w2 + g1.w * w3;
      a2 += g2.x * w0 + g2.y * w1 + g2.z * w2 + g2.w * w3;
      a3 += g3.x * w0 + g3.y * w1 + g3.z * w2 + g3.w * w3;
    }
    part[sub][0][k] = a0;
    part[sub][1][k] = a1;
    part[sub][2][k] = a2;
    part[sub][3][k] = a3;
    __syncthreads();

    if (t < D1) {
      #pragma unroll
      for (int e = 0; e < 4; ++e) {
        P[((size_t)c * Bn + (e0 + e)) * D1 + t] = part[0][e][t] + part[1][e][t];
      }
    }
    return;
  }

  // ---- pool: R2-exact span mean-pool ----
  if (t >= 192) return;              // wave 3 retires immediately
  const int bb = blockIdx.x - NH;
  const int b = bb >> 1;
  const int p = bb & 1;
  const float4* base = reinterpret_cast<const float4*>(feat) + (size_t)b * (S * HV);

  const int s0 = start[b];
  const int s1 = endp[b];
  float4 a0{0,0,0,0}, a1{0,0,0,0}, a2{0,0,0,0}, a3{0,0,0,0};
  int s = s0 + p;
  for (; s + 6 < s1; s += 8) {
    float4 v0 = base[(size_t)(s    ) * HV + t];
    float4 v1 = base[(size_t)(s + 2) * HV + t];
    float4 v2 = base[(size_t)(s + 4) * HV + t];
    float4 v3 = base[(size_t)(s + 6) * HV + t];
    a0.x += v0.x; a0.y += v0.y; a0.z += v0.z; a0.w += v0.w;
    a1.x += v1.x; a1.y += v1.y; a1.z += v1.z; a1.w += v1.w;
    a2.x += v2.x; a2.y += v2.y; a2.z += v2.z; a2.w += v2.w;
    a3.x += v3.x; a3.y += v3.y; a3.z += v3.z; a3.w += v3.w;
  }
  for (; s < s1; s += 2) {
    float4 v = base[(size_t)s * HV + t];
    a0.x += v.x; a0.y += v.y; a0.z += v.z; a0.w += v.w;
  }
  const float inv = 1.0f / (float)(s1 - s0);
  float4 r;
  r.x = ((a0.x + a1.x) + (a2.x + a3.x)) * inv;
  r.y = ((a0.y + a1.y) + (a2.y + a3.y)) * inv;
  r.z = ((a0.z + a1.z) + (a2.z + a3.z)) * inv;
  r.w = ((a0.w + a1.w) + (a2.w + a3.w)) * inv;
  reinterpret_cast<float4*>(gp)[((size_t)p * Bn + b) * HV + t] = r;
}

// Launch 2: CRC head + finalize, 4-example blocks (same W1 reuse as R8).
// Block = 4 examples x BOTH CRC chunks (768 rows); grid 256 x 256 thr.
// thread = (k = t&127, sub = t>>7 -> 384-row half). After partials:
// one wave per example combines CLS partials P + CRC partials, relu, W2,
// butterfly-reduce, sigmoid, store.
__global__ __launch_bounds__(256) void crc_head_finalize(
    const float* __restrict__ gp, const float* __restrict__ W1,
    const float* __restrict__ P, const float* __restrict__ b1,
    const float* __restrict__ W2, const float* __restrict__ b2,
    float* __restrict__ out) {
  __shared__ float g[4][768];        // 12 KB: 4 examples' full CRC features
  __shared__ float part[2][4][D1];   // 4 KB: [sub][e][k]

  const int t = threadIdx.x;
  const int e0 = blockIdx.x * 4;

  // Stage g: crc = gp0 + gp1 for 4 examples (768 float4)
  for (int i = t; i < 768; i += 256) {
    const int e = i / 192;
    const int j = i % 192;
    const float* b0 = gp + (size_t)(e0 + e) * H;
    float4 u0 = reinterpret_cast<const float4*>(b0)[j];
    float4 u1 = reinterpret_cast<const float4*>(b0 + (size_t)Bn * H)[j];
    float4 v;
    v.x = u0.x + u1.x; v.y = u0.y + u1.y;
    v.z = u0.z + u1.z; v.w = u0.w + u1.w;
    reinterpret_cast<float4*>(&g[e][0])[j] = v;
  }
  __syncthreads();

  const int k = t & (D1 - 1);
  const int sub = t >> 7;            // which 384-row half of the CRC
  const int gofs = sub * 384;
  const float* Wc = W1 + (size_t)(H + gofs) * D1 + k;

  float a0 = 0.f, a1 = 0.f, a2 = 0.f, a3 = 0.f;
  #pragma unroll 4
  for (int d = 0; d < 384; d += 4) {
    float w0 = Wc[(size_t)(d + 0) * D1];
    float w1 = Wc[(size_t)(d + 1) * D1];
    float w2 = Wc[(size_t)(d + 2) * D1];
    float w3 = Wc[(size_t)(d + 3) * D1];
    float4 g0 = *reinterpret_cast<const float4*>(&g[0][gofs + d]);
    float4 g1 = *reinterpret_cast<const float4*>(&g[1][gofs + d]);
    float4 g2 = *reinterpret_cast<const float4*>(&g[2][gofs + d]);
    float4 g3 = *reinterpret_cast<const float4*>(&g[3][gofs + d]);
    a0 += g0.x * w0 + g0.y * w1 + g0.z * w2 + g0.w * w3;
    a1 += g1.x * w0 + g1.y * w1 + g1.z * w2 + g1.w * w3;
    a2 += g2.x * w0 + g2.y * w1 + g2.z * w2 + g2.w * w3;
    a3 += g3.x * w0 + g3.y * w1 + g3.z * w2 + g3.w * w3;
  }
  part[sub][0][k] = a0;
  part[sub][1][k] = a1;
  part[sub][2][k] = a2;
  part[sub][3][k] = a3;
  __syncthreads();

  // Finalize: wave w owns example e0+w; lane l owns k-pair (l, l+64).
  {
    const int w = t >> 6, l = t & 63;
    const int e = e0 + w;
    const int k0 = l, k1 = l + 64;
    float h0 = b1[k0] + part[0][w][k0] + part[1][w][k0]
             + P[((size_t)0 * Bn + e) * D1 + k0]
             + P[((size_t)1 * Bn + e) * D1 + k0];
    float h1 = b1[k1] + part[0][w][k1] + part[1][w][k1]
             + P[((size_t)0 * Bn + e) * D1 + k1]
             + P[((size_t)1 * Bn + e) * D1 + k1];
    h0 = fmaxf(h0, 0.f); h1 = fmaxf(h1, 0.f);
    float v = h0 * W2[k0] + h1 * W2[k1];
    #pragma unroll
    for (int off = 32; off > 0; off >>= 1) v += __shfl_down(v, off);
    if (l == 0) out[e] = 1.0f / (1.0f + expf(-(v + b2[0])));
  }
}

extern "C" void kernel_launch(void* const* d_in, const int* in_sizes, int n_in,
                              void* d_out, int out_size, void* d_ws, size_t ws_size,
                              hipStream_t stream) {
  const float* feat = (const float*)d_in[0];   // [B,S,H] fp32
  const int* start  = (const int*)d_in[1];     // [B]
  const int* endp   = (const int*)d_in[2];     // [B]
  const float* W1   = (const float*)d_in[3];   // [2H,D1]
  const float* b1   = (const float*)d_in[4];   // [D1]
  const float* W2   = (const float*)d_in[5];   // [D1,1]
  const float* b2   = (const float*)d_in[6];   // [1]
  float* out = (float*)d_out;                  // [B]

  float* wsf = (float*)d_ws;
  float* gp  = wsf;                            // [2][Bn][768]
  float* P   = gp + (size_t)2 * Bn * H;        // [2][Bn][D1]

  hipLaunchKernelGGL(fused_pool_clshead, dim3(NH + Bn * 2), dim3(256), 0,
                     stream, feat, start, endp, gp, W1, P);
  hipLaunchKernelGGL(crc_head_finalize, dim3(Bn / 4), dim3(256), 0, stream,
                     gp, W1, P, b1, W2, b2, out);
}